// Round 1
// baseline (559.248 us; speedup 1.0000x reference)
//
#include <hip/hip_runtime.h>
#include <hip/hip_bf16.h>

#define N 8192
#define IND 128
#define OUTD 128

typedef float f32x4 __attribute__((ext_vector_type(4)));
typedef short s16x8 __attribute__((ext_vector_type(8)));

static __device__ inline unsigned short f2bf(float f) {
    union { float f; unsigned u; } v; v.f = f;
    unsigned u = v.u + 0x7fffu + ((v.u >> 16) & 1u);
    return (unsigned short)(u >> 16);
}
static __device__ inline float bf2f(unsigned short b) {
    union { unsigned u; float f; } v; v.u = ((unsigned)b) << 16;
    return v.f;
}

// ---------------------------------------------------------------------------
// Kernel 1: h = x @ W  (bf16 MFMA), store transposed bf16 hT[c][i] (128 x N)
// so the main kernel's B-fragments are contiguous 16B loads.
// Block = 256 thr (4 waves), 64 rows per block. W staged in LDS bf16,
// pitch 130 to kill the 4-way quad bank conflict (8q*65 mod 32 = 8q).
// ---------------------------------------------------------------------------
__global__ __launch_bounds__(256) void k1_xw(const float* __restrict__ x,
                                             const float* __restrict__ W,
                                             unsigned short* __restrict__ hT) {
    __shared__ unsigned short Wl[128 * 130];
    const int tid = threadIdx.x;
    {
        int k = tid >> 1, n0 = (tid & 1) * 64;
        const float4* src = (const float4*)(W + k * 128 + n0);
#pragma unroll
        for (int v = 0; v < 16; ++v) {
            float4 f = src[v];
            int base = k * 130 + n0 + v * 4;
            Wl[base + 0] = f2bf(f.x);
            Wl[base + 1] = f2bf(f.y);
            Wl[base + 2] = f2bf(f.z);
            Wl[base + 3] = f2bf(f.w);
        }
    }
    __syncthreads();
    const int wave = tid >> 6, lane = tid & 63;
    const int m = lane & 15, quad = lane >> 4;
    const int ibase = blockIdx.x * 64 + wave * 16;
    const int irow = ibase + m;

    f32x4 acc[8];
#pragma unroll
    for (int t = 0; t < 8; ++t) acc[t] = (f32x4){0.f, 0.f, 0.f, 0.f};

#pragma unroll
    for (int ks = 0; ks < 4; ++ks) {
        const int k0 = ks * 32 + quad * 8;
        const float4* xp = (const float4*)(x + (size_t)irow * 128 + k0);
        float4 xa = xp[0], xb = xp[1];
        s16x8 afrag;
        afrag[0] = (short)f2bf(xa.x); afrag[1] = (short)f2bf(xa.y);
        afrag[2] = (short)f2bf(xa.z); afrag[3] = (short)f2bf(xa.w);
        afrag[4] = (short)f2bf(xb.x); afrag[5] = (short)f2bf(xb.y);
        afrag[6] = (short)f2bf(xb.z); afrag[7] = (short)f2bf(xb.w);
#pragma unroll
        for (int nt = 0; nt < 8; ++nt) {
            const int n = nt * 16 + m;
            s16x8 bfrag;
#pragma unroll
            for (int j = 0; j < 8; ++j)
                bfrag[j] = (short)Wl[(k0 + j) * 130 + n];
            acc[nt] = __builtin_amdgcn_mfma_f32_16x16x32_bf16(afrag, bfrag, acc[nt], 0, 0, 0);
        }
    }
    // C/D layout: col = lane&15, row = quad*4 + reg  -> 4 consecutive node idx
#pragma unroll
    for (int nt = 0; nt < 8; ++nt) {
        const int c = nt * 16 + m;
        const int i0 = ibase + quad * 4;
        ushort4 pk;
        pk.x = f2bf(acc[nt][0]); pk.y = f2bf(acc[nt][1]);
        pk.z = f2bf(acc[nt][2]); pk.w = f2bf(acc[nt][3]);
        *(ushort4*)(hT + (size_t)c * N + i0) = pk;
    }
}

// ---------------------------------------------------------------------------
// Kernel 2: e_src/e_dst per (node, head) from hT, then the 6 separable arrays:
// A=exp(es), C=exp(.2 es), T=-es (cond threshold), B=exp(ed), D=exp(.2 ed), E=ed
// ---------------------------------------------------------------------------
__global__ __launch_bounds__(256) void k2_e(const unsigned short* __restrict__ hT,
                                            const float* __restrict__ a_src,
                                            const float* __restrict__ a_dst,
                                            float* __restrict__ Aa, float* __restrict__ Ca,
                                            float* __restrict__ Ta, float* __restrict__ Ba,
                                            float* __restrict__ Da, float* __restrict__ Ea) {
    const int i = blockIdx.x * 256 + threadIdx.x;
    float es0 = 0.f, ed0 = 0.f, es1 = 0.f, ed1 = 0.f;
#pragma unroll 8
    for (int c = 0; c < 128; ++c) {
        float v = bf2f(hT[(size_t)c * N + i]);
        float as = a_src[c], ad = a_dst[c];
        if (c < 64) { es0 += v * as; ed0 += v * ad; }
        else        { es1 += v * as; ed1 += v * ad; }
    }
    Aa[i] = __expf(es0);        Aa[N + i] = __expf(es1);
    Ca[i] = __expf(0.2f * es0); Ca[N + i] = __expf(0.2f * es1);
    Ta[i] = -es0;               Ta[N + i] = -es1;
    Ba[i] = __expf(ed0);        Ba[N + i] = __expf(ed1);
    Da[i] = __expf(0.2f * ed0); Da[N + i] = __expf(0.2f * ed1);
    Ea[i] = ed0;                Ea[N + i] = ed1;
}

// ---------------------------------------------------------------------------
// Kernel 3 (main): stream adj, build P-fragments in registers, MFMA against hT.
// grid = (128 i-tiles, JC j-chunks); block = 256 thr = 4 waves, 16 rows/wave.
// Writes unnormalized partials U (fp32) and row-sums L to ws.
// ---------------------------------------------------------------------------
__global__ __launch_bounds__(256) void k3_main(const float* __restrict__ adj,
                                               const unsigned short* __restrict__ hT,
                                               const float* __restrict__ Aa,
                                               const float* __restrict__ Ca,
                                               const float* __restrict__ Ta,
                                               const float* __restrict__ Ba,
                                               const float* __restrict__ Da,
                                               const float* __restrict__ Ea,
                                               float* __restrict__ Up,
                                               float* __restrict__ Lp,
                                               int jlen) {
    const int tid = threadIdx.x;
    const int wave = tid >> 6, lane = tid & 63;
    const int m = lane & 15, quad = lane >> 4;
    const int ibase = blockIdx.x * 64 + wave * 16;
    const int irow = ibase + m;
    const int jc = blockIdx.y;
    const int j0 = jc * jlen;

    const float A0 = Aa[irow], C0 = Ca[irow], T0 = Ta[irow];
    const float A1 = Aa[N + irow], C1 = Ca[N + irow], T1 = Ta[N + irow];

    f32x4 acc[2][4];
#pragma unroll
    for (int h = 0; h < 2; ++h)
#pragma unroll
        for (int nt = 0; nt < 4; ++nt) acc[h][nt] = (f32x4){0.f, 0.f, 0.f, 0.f};
    float ls0 = 0.f, ls1 = 0.f;

    const float* adjrow = adj + (size_t)irow * N;
    const int steps = jlen >> 5;

#pragma unroll 2
    for (int s = 0; s < steps; ++s) {
        const int jq = j0 + s * 32 + quad * 8;  // this lane's 8 j's
        float ajv[8], b0[8], d0[8], e0[8], b1[8], d1[8], e1[8];
        *(float4*)(ajv)     = *(const float4*)(adjrow + jq);
        *(float4*)(ajv + 4) = *(const float4*)(adjrow + jq + 4);
        *(float4*)(b0)      = *(const float4*)(Ba + jq);
        *(float4*)(b0 + 4)  = *(const float4*)(Ba + jq + 4);
        *(float4*)(d0)      = *(const float4*)(Da + jq);
        *(float4*)(d0 + 4)  = *(const float4*)(Da + jq + 4);
        *(float4*)(e0)      = *(const float4*)(Ea + jq);
        *(float4*)(e0 + 4)  = *(const float4*)(Ea + jq + 4);
        *(float4*)(b1)      = *(const float4*)(Ba + N + jq);
        *(float4*)(b1 + 4)  = *(const float4*)(Ba + N + jq + 4);
        *(float4*)(d1)      = *(const float4*)(Da + N + jq);
        *(float4*)(d1 + 4)  = *(const float4*)(Da + N + jq + 4);
        *(float4*)(e1)      = *(const float4*)(Ea + N + jq);
        *(float4*)(e1 + 4)  = *(const float4*)(Ea + N + jq + 4);

        s16x8 p0, p1;
#pragma unroll
        for (int jj = 0; jj < 8; ++jj) {
            float w0 = (e0[jj] > T0) ? A0 * b0[jj] : C0 * d0[jj];
            float pv0 = ajv[jj] * w0;
            ls0 += pv0;
            p0[jj] = (short)f2bf(pv0);
            float w1 = (e1[jj] > T1) ? A1 * b1[jj] : C1 * d1[jj];
            float pv1 = ajv[jj] * w1;
            ls1 += pv1;
            p1[jj] = (short)f2bf(pv1);
        }
#pragma unroll
        for (int nt = 0; nt < 4; ++nt) {
            const int c0 = nt * 16 + m;
            s16x8 h0 = *(const s16x8*)(hT + (size_t)c0 * N + jq);
            s16x8 h1 = *(const s16x8*)(hT + (size_t)(c0 + 64) * N + jq);
            acc[0][nt] = __builtin_amdgcn_mfma_f32_16x16x32_bf16(p0, h0, acc[0][nt], 0, 0, 0);
            acc[1][nt] = __builtin_amdgcn_mfma_f32_16x16x32_bf16(p1, h1, acc[1][nt], 0, 0, 0);
        }
    }

    // full row sums across the 4 quads (each quad covered a disjoint j subset)
    ls0 += __shfl_xor(ls0, 16, 64);
    ls0 += __shfl_xor(ls0, 32, 64);
    ls1 += __shfl_xor(ls1, 16, 64);
    ls1 += __shfl_xor(ls1, 32, 64);

    float* Ub = Up + (size_t)jc * N * 128;
#pragma unroll
    for (int h = 0; h < 2; ++h)
#pragma unroll
        for (int nt = 0; nt < 4; ++nt) {
            const int c = h * 64 + nt * 16 + m;
            const int ib = ibase + quad * 4;
#pragma unroll
            for (int r = 0; r < 4; ++r)
                Ub[(size_t)(ib + r) * 128 + c] = acc[h][nt][r];
        }
    if (quad == 0) {
        Lp[((size_t)jc * 2 + 0) * N + irow] = ls0;
        Lp[((size_t)jc * 2 + 1) * N + irow] = ls1;
    }
}

// ---------------------------------------------------------------------------
// Kernel 4: sum partials over j-chunks, divide by row-sum, write out (fp32)
// ---------------------------------------------------------------------------
__global__ __launch_bounds__(256) void k4_reduce(const float* __restrict__ Up,
                                                 const float* __restrict__ Lp,
                                                 float* __restrict__ out, int JC) {
    const int idx = blockIdx.x * 256 + threadIdx.x;
    const int i = idx >> 7, c = idx & 127, h = c >> 6;
    float su = 0.f, sl = 0.f;
    for (int jcc = 0; jcc < JC; ++jcc) {
        su += Up[(size_t)jcc * N * 128 + idx];
        sl += Lp[((size_t)jcc * 2 + h) * N + i];
    }
    out[idx] = su / sl;
}

extern "C" void kernel_launch(void* const* d_in, const int* in_sizes, int n_in,
                              void* d_out, int out_size, void* d_ws, size_t ws_size,
                              hipStream_t stream) {
    const float* x     = (const float*)d_in[0];
    const float* adj   = (const float*)d_in[1];
    const float* W     = (const float*)d_in[2];
    const float* a_src = (const float*)d_in[3];
    const float* a_dst = (const float*)d_in[4];
    float* out = (float*)d_out;
    char* ws = (char*)d_ws;

    size_t off = 0;
    unsigned short* hT = (unsigned short*)(ws + off); off += (size_t)128 * N * 2;
    float* Aa = (float*)(ws + off); off += (size_t)2 * N * 4;
    float* Ca = (float*)(ws + off); off += (size_t)2 * N * 4;
    float* Ta = (float*)(ws + off); off += (size_t)2 * N * 4;
    float* Ba = (float*)(ws + off); off += (size_t)2 * N * 4;
    float* Da = (float*)(ws + off); off += (size_t)2 * N * 4;
    float* Ea = (float*)(ws + off); off += (size_t)2 * N * 4;

    int JC = 4;
    while (JC > 1) {
        size_t need = off + (size_t)JC * N * 128 * 4 + (size_t)JC * 2 * N * 4;
        if (need <= ws_size) break;
        JC >>= 1;
    }
    float* Up = (float*)(ws + off);
    float* Lp = (float*)(ws + off + (size_t)JC * N * 128 * 4);

    k1_xw<<<N / 64, 256, 0, stream>>>(x, W, hT);
    k2_e<<<N / 256, 256, 0, stream>>>(hT, a_src, a_dst, Aa, Ca, Ta, Ba, Da, Ea);
    dim3 g3(N / 64, JC);
    k3_main<<<g3, 256, 0, stream>>>(adj, hT, Aa, Ca, Ta, Ba, Da, Ea, Up, Lp, N / JC);
    k4_reduce<<<(N * 128) / 256, 256, 0, stream>>>(Up, Lp, out, JC);
}

// Round 2
// 542.369 us; speedup vs baseline: 1.0311x; 1.0311x over previous
//
#include <hip/hip_runtime.h>
#include <hip/hip_bf16.h>

#define N 8192
#define IND 128
#define OUTD 128

typedef float f32x4 __attribute__((ext_vector_type(4)));
typedef short s16x8 __attribute__((ext_vector_type(8)));
typedef _Float16 f16;
typedef _Float16 f16x4 __attribute__((ext_vector_type(4)));

static __device__ inline unsigned short f2bf(float f) {
    union { float f; unsigned u; } v; v.f = f;
    unsigned u = v.u + 0x7fffu + ((v.u >> 16) & 1u);
    return (unsigned short)(u >> 16);
}
static __device__ inline float bf2f(unsigned short b) {
    union { unsigned u; float f; } v; v.u = ((unsigned)b) << 16;
    return v.f;
}

// ---------------------------------------------------------------------------
// Kernel 1: h = x @ W  (bf16 MFMA), store transposed bf16 hT[c][i] (128 x N)
// so the main kernel's B-fragments are contiguous 16B loads.
// ---------------------------------------------------------------------------
__global__ __launch_bounds__(256) void k1_xw(const float* __restrict__ x,
                                             const float* __restrict__ W,
                                             unsigned short* __restrict__ hT) {
    __shared__ unsigned short Wl[128 * 130];
    const int tid = threadIdx.x;
    {
        int k = tid >> 1, n0 = (tid & 1) * 64;
        const float4* src = (const float4*)(W + k * 128 + n0);
#pragma unroll
        for (int v = 0; v < 16; ++v) {
            float4 f = src[v];
            int base = k * 130 + n0 + v * 4;
            Wl[base + 0] = f2bf(f.x);
            Wl[base + 1] = f2bf(f.y);
            Wl[base + 2] = f2bf(f.z);
            Wl[base + 3] = f2bf(f.w);
        }
    }
    __syncthreads();
    const int wave = tid >> 6, lane = tid & 63;
    const int m = lane & 15, quad = lane >> 4;
    const int ibase = blockIdx.x * 64 + wave * 16;
    const int irow = ibase + m;

    f32x4 acc[8];
#pragma unroll
    for (int t = 0; t < 8; ++t) acc[t] = (f32x4){0.f, 0.f, 0.f, 0.f};

#pragma unroll
    for (int ks = 0; ks < 4; ++ks) {
        const int k0 = ks * 32 + quad * 8;
        const float4* xp = (const float4*)(x + (size_t)irow * 128 + k0);
        float4 xa = xp[0], xb = xp[1];
        s16x8 afrag;
        afrag[0] = (short)f2bf(xa.x); afrag[1] = (short)f2bf(xa.y);
        afrag[2] = (short)f2bf(xa.z); afrag[3] = (short)f2bf(xa.w);
        afrag[4] = (short)f2bf(xb.x); afrag[5] = (short)f2bf(xb.y);
        afrag[6] = (short)f2bf(xb.z); afrag[7] = (short)f2bf(xb.w);
#pragma unroll
        for (int nt = 0; nt < 8; ++nt) {
            const int n = nt * 16 + m;
            s16x8 bfrag;
#pragma unroll
            for (int j = 0; j < 8; ++j)
                bfrag[j] = (short)Wl[(k0 + j) * 130 + n];
            acc[nt] = __builtin_amdgcn_mfma_f32_16x16x32_bf16(afrag, bfrag, acc[nt], 0, 0, 0);
        }
    }
#pragma unroll
    for (int nt = 0; nt < 8; ++nt) {
        const int c = nt * 16 + m;
        const int i0 = ibase + quad * 4;
        ushort4 pk;
        pk.x = f2bf(acc[nt][0]); pk.y = f2bf(acc[nt][1]);
        pk.z = f2bf(acc[nt][2]); pk.w = f2bf(acc[nt][3]);
        *(ushort4*)(hT + (size_t)c * N + i0) = pk;
    }
}

// ---------------------------------------------------------------------------
// Kernel 2: per-node scores -> separable arrays.
// w_ij = exp(leaky(e_src_i + e_dst_j)) = max(A_i*B_j, C_i*D_j)
//   A=exp(es), C=exp(0.2 es)  (per i, per head)
//   BD[j] = {B0, D0, B1, D1} = {exp(ed0), exp(0.2 ed0), exp(ed1), exp(0.2 ed1)}
// ---------------------------------------------------------------------------
__global__ __launch_bounds__(256) void k2_e(const unsigned short* __restrict__ hT,
                                            const float* __restrict__ a_src,
                                            const float* __restrict__ a_dst,
                                            float* __restrict__ As, float* __restrict__ Cs,
                                            float4* __restrict__ BD) {
    const int i = blockIdx.x * 256 + threadIdx.x;
    float es0 = 0.f, ed0 = 0.f, es1 = 0.f, ed1 = 0.f;
#pragma unroll 8
    for (int c = 0; c < 128; ++c) {
        float v = bf2f(hT[(size_t)c * N + i]);
        float as = a_src[c], ad = a_dst[c];
        if (c < 64) { es0 += v * as; ed0 += v * ad; }
        else        { es1 += v * as; ed1 += v * ad; }
    }
    As[i]     = __expf(es0);
    As[N + i] = __expf(es1);
    Cs[i]     = __expf(0.2f * es0);
    Cs[N + i] = __expf(0.2f * es1);
    float4 bd;
    bd.x = __expf(ed0); bd.y = __expf(0.2f * ed0);
    bd.z = __expf(ed1); bd.w = __expf(0.2f * ed1);
    BD[i] = bd;
}

// ---------------------------------------------------------------------------
// Kernel 3 (main): stream adj, build P-fragments in registers, MFMA vs hT.
// grid = (128 i-tiles, JC j-chunks); block = 256 thr = 4 waves, 16 rows/wave.
// Unnormalized partials to Up (fp16), row-sums to Lp (fp32).
// ---------------------------------------------------------------------------
__global__ __launch_bounds__(256, 4) void k3_main(const float* __restrict__ adj,
                                                  const unsigned short* __restrict__ hT,
                                                  const float* __restrict__ As,
                                                  const float* __restrict__ Cs,
                                                  const float4* __restrict__ BD,
                                                  f16* __restrict__ Up,
                                                  float* __restrict__ Lp,
                                                  int jlen) {
    const int tid = threadIdx.x;
    const int wave = tid >> 6, lane = tid & 63;
    const int m = lane & 15, quad = lane >> 4;
    const int ibase = blockIdx.x * 64 + wave * 16;
    const int irow = ibase + m;
    const int jc = blockIdx.y;
    const int j0 = jc * jlen;

    const float A0 = As[irow], C0 = Cs[irow];
    const float A1 = As[N + irow], C1 = Cs[N + irow];

    f32x4 acc[2][4];
#pragma unroll
    for (int h = 0; h < 2; ++h)
#pragma unroll
        for (int nt = 0; nt < 4; ++nt) acc[h][nt] = (f32x4){0.f, 0.f, 0.f, 0.f};
    float ls0 = 0.f, ls1 = 0.f;

    const float* adjrow = adj + (size_t)irow * N;
    const int steps = jlen >> 5;

#pragma unroll 2
    for (int s = 0; s < steps; ++s) {
        const int jq = j0 + s * 32 + quad * 8;  // this lane's 8 j's
        float aj[8];
        *(float4*)(aj)     = *(const float4*)(adjrow + jq);
        *(float4*)(aj + 4) = *(const float4*)(adjrow + jq + 4);
        float4 bd[8];
#pragma unroll
        for (int jj = 0; jj < 8; ++jj) bd[jj] = BD[jq + jj];

        s16x8 p0, p1;
#pragma unroll
        for (int jj = 0; jj < 8; ++jj) {
            float w0 = fmaxf(A0 * bd[jj].x, C0 * bd[jj].y);
            float pv0 = aj[jj] * w0;
            ls0 += pv0;
            p0[jj] = (short)f2bf(pv0);
            float w1 = fmaxf(A1 * bd[jj].z, C1 * bd[jj].w);
            float pv1 = aj[jj] * w1;
            ls1 += pv1;
            p1[jj] = (short)f2bf(pv1);
        }
#pragma unroll
        for (int nt = 0; nt < 4; ++nt) {
            const int c0 = nt * 16 + m;
            s16x8 h0 = *(const s16x8*)(hT + (size_t)c0 * N + jq);
            s16x8 h1 = *(const s16x8*)(hT + (size_t)(c0 + 64) * N + jq);
            acc[0][nt] = __builtin_amdgcn_mfma_f32_16x16x32_bf16(p0, h0, acc[0][nt], 0, 0, 0);
            acc[1][nt] = __builtin_amdgcn_mfma_f32_16x16x32_bf16(p1, h1, acc[1][nt], 0, 0, 0);
        }
    }

    // full row sums across quads (each quad covered a disjoint j subset)
    ls0 += __shfl_xor(ls0, 16, 64);
    ls0 += __shfl_xor(ls0, 32, 64);
    ls1 += __shfl_xor(ls1, 16, 64);
    ls1 += __shfl_xor(ls1, 32, 64);

    f16* Ub = Up + (size_t)jc * N * 128;
#pragma unroll
    for (int h = 0; h < 2; ++h)
#pragma unroll
        for (int nt = 0; nt < 4; ++nt) {
            const int c = h * 64 + nt * 16 + m;
            const int ib = ibase + quad * 4;
#pragma unroll
            for (int r = 0; r < 4; ++r)
                Ub[(size_t)(ib + r) * 128 + c] = (f16)acc[h][nt][r];
        }
    if (quad == 0) {
        Lp[((size_t)jc * 2 + 0) * N + irow] = ls0;
        Lp[((size_t)jc * 2 + 1) * N + irow] = ls1;
    }
}

// ---------------------------------------------------------------------------
// Kernel 4: sum fp16 partials over j-chunks, divide by row-sum. 4 elems/thread.
// ---------------------------------------------------------------------------
__global__ __launch_bounds__(256) void k4_reduce(const f16* __restrict__ Up,
                                                 const float* __restrict__ Lp,
                                                 float* __restrict__ out, int JC) {
    const int base = (blockIdx.x * 256 + threadIdx.x) * 4;
    const int i = base >> 7, c = base & 127, h = c >> 6;
    float su0 = 0.f, su1 = 0.f, su2 = 0.f, su3 = 0.f, sl = 0.f;
    for (int jcc = 0; jcc < JC; ++jcc) {
        f16x4 u = *(const f16x4*)(Up + (size_t)jcc * N * 128 + base);
        su0 += (float)u[0]; su1 += (float)u[1];
        su2 += (float)u[2]; su3 += (float)u[3];
        sl += Lp[((size_t)jcc * 2 + h) * N + i];
    }
    float inv = 1.0f / sl;
    float4 o; o.x = su0 * inv; o.y = su1 * inv; o.z = su2 * inv; o.w = su3 * inv;
    *(float4*)(out + base) = o;
}

extern "C" void kernel_launch(void* const* d_in, const int* in_sizes, int n_in,
                              void* d_out, int out_size, void* d_ws, size_t ws_size,
                              hipStream_t stream) {
    const float* x     = (const float*)d_in[0];
    const float* adj   = (const float*)d_in[1];
    const float* W     = (const float*)d_in[2];
    const float* a_src = (const float*)d_in[3];
    const float* a_dst = (const float*)d_in[4];
    float* out = (float*)d_out;
    char* ws = (char*)d_ws;

    size_t off = 0;
    unsigned short* hT = (unsigned short*)(ws + off); off += (size_t)128 * N * 2;
    float* As = (float*)(ws + off); off += (size_t)2 * N * 4;
    float* Cs = (float*)(ws + off); off += (size_t)2 * N * 4;
    float4* BD = (float4*)(ws + off); off += (size_t)N * 16;

    int JC = 8;
    while (JC > 1) {
        size_t need = off + (size_t)JC * N * 128 * 2 + (size_t)JC * 2 * N * 4;
        if (need <= ws_size) break;
        JC >>= 1;
    }
    f16* Up = (f16*)(ws + off);
    float* Lp = (float*)(ws + off + (size_t)JC * N * 128 * 2);

    k1_xw<<<N / 64, 256, 0, stream>>>(x, W, hT);
    k2_e<<<N / 256, 256, 0, stream>>>(hT, a_src, a_dst, As, Cs, BD);
    dim3 g3(N / 64, JC);
    k3_main<<<g3, 256, 0, stream>>>(adj, hT, As, Cs, BD, Up, Lp, N / JC);
    k4_reduce<<<(N * 128) / (256 * 4), 256, 0, stream>>>(Up, Lp, out, JC);
}

// Round 3
// 538.924 us; speedup vs baseline: 1.0377x; 1.0064x over previous
//
#include <hip/hip_runtime.h>
#include <hip/hip_bf16.h>

#define N 8192
#define IND 128
#define OUTD 128
#define JC 8
#define JLEN 1024   /* N/JC */
#define STEPS 32    /* JLEN/32 */

typedef float f32x4 __attribute__((ext_vector_type(4)));
typedef short s16x8 __attribute__((ext_vector_type(8)));
typedef _Float16 f16;
typedef _Float16 f16x4 __attribute__((ext_vector_type(4)));

static __device__ inline unsigned short f2bf(float f) {
    union { float f; unsigned u; } v; v.f = f;
    unsigned u = v.u + 0x7fffu + ((v.u >> 16) & 1u);
    return (unsigned short)(u >> 16);
}
static __device__ inline float bf2f(unsigned short b) {
    union { unsigned u; float f; } v; v.u = ((unsigned)b) << 16;
    return v.f;
}

// ---------------------------------------------------------------------------
// Kernel 1: h = x @ W  (bf16 MFMA), store transposed bf16 hT[c][i] (128 x N).
// ---------------------------------------------------------------------------
__global__ __launch_bounds__(256) void k1_xw(const float* __restrict__ x,
                                             const float* __restrict__ W,
                                             unsigned short* __restrict__ hT) {
    __shared__ unsigned short Wl[128 * 130];
    const int tid = threadIdx.x;
    {
        int k = tid >> 1, n0 = (tid & 1) * 64;
        const float4* src = (const float4*)(W + k * 128 + n0);
#pragma unroll
        for (int v = 0; v < 16; ++v) {
            float4 f = src[v];
            int base = k * 130 + n0 + v * 4;
            Wl[base + 0] = f2bf(f.x);
            Wl[base + 1] = f2bf(f.y);
            Wl[base + 2] = f2bf(f.z);
            Wl[base + 3] = f2bf(f.w);
        }
    }
    __syncthreads();
    const int wave = tid >> 6, lane = tid & 63;
    const int m = lane & 15, quad = lane >> 4;
    const int ibase = blockIdx.x * 64 + wave * 16;
    const int irow = ibase + m;

    f32x4 acc[8];
#pragma unroll
    for (int t = 0; t < 8; ++t) acc[t] = (f32x4){0.f, 0.f, 0.f, 0.f};

#pragma unroll
    for (int ks = 0; ks < 4; ++ks) {
        const int k0 = ks * 32 + quad * 8;
        const float4* xp = (const float4*)(x + (size_t)irow * 128 + k0);
        float4 xa = xp[0], xb = xp[1];
        s16x8 afrag;
        afrag[0] = (short)f2bf(xa.x); afrag[1] = (short)f2bf(xa.y);
        afrag[2] = (short)f2bf(xa.z); afrag[3] = (short)f2bf(xa.w);
        afrag[4] = (short)f2bf(xb.x); afrag[5] = (short)f2bf(xb.y);
        afrag[6] = (short)f2bf(xb.z); afrag[7] = (short)f2bf(xb.w);
#pragma unroll
        for (int nt = 0; nt < 8; ++nt) {
            const int n = nt * 16 + m;
            s16x8 bfrag;
#pragma unroll
            for (int j = 0; j < 8; ++j)
                bfrag[j] = (short)Wl[(k0 + j) * 130 + n];
            acc[nt] = __builtin_amdgcn_mfma_f32_16x16x32_bf16(afrag, bfrag, acc[nt], 0, 0, 0);
        }
    }
#pragma unroll
    for (int nt = 0; nt < 8; ++nt) {
        const int c = nt * 16 + m;
        const int i0 = ibase + quad * 4;
        ushort4 pk;
        pk.x = f2bf(acc[nt][0]); pk.y = f2bf(acc[nt][1]);
        pk.z = f2bf(acc[nt][2]); pk.w = f2bf(acc[nt][3]);
        *(ushort4*)(hT + (size_t)c * N + i0) = pk;
    }
}

// ---------------------------------------------------------------------------
// Kernel 2: per-node separable arrays.
// w_ij = exp(leaky(es_i + ed_j)) = max(A_i*B_j, C_i*D_j)
// BD[j] = {B0, D0, B1, D1}
// ---------------------------------------------------------------------------
__global__ __launch_bounds__(256) void k2_e(const unsigned short* __restrict__ hT,
                                            const float* __restrict__ a_src,
                                            const float* __restrict__ a_dst,
                                            float* __restrict__ As, float* __restrict__ Cs,
                                            float4* __restrict__ BD) {
    const int i = blockIdx.x * 256 + threadIdx.x;
    float es0 = 0.f, ed0 = 0.f, es1 = 0.f, ed1 = 0.f;
#pragma unroll 8
    for (int c = 0; c < 128; ++c) {
        float v = bf2f(hT[(size_t)c * N + i]);
        float as = a_src[c], ad = a_dst[c];
        if (c < 64) { es0 += v * as; ed0 += v * ad; }
        else        { es1 += v * as; ed1 += v * ad; }
    }
    As[i]     = __expf(es0);
    As[N + i] = __expf(es1);
    Cs[i]     = __expf(0.2f * es0);
    Cs[N + i] = __expf(0.2f * es1);
    float4 bd;
    bd.x = __expf(ed0); bd.y = __expf(0.2f * ed0);
    bd.z = __expf(ed1); bd.w = __expf(0.2f * ed1);
    BD[i] = bd;
}

// ---------------------------------------------------------------------------
// Kernel 3 (main): adj register-prefetched (HBM stream), hT loads hoisted to
// top of step (L2 stream, hidden by P-compute), BD broadcast from LDS.
// grid = (128 i-tiles, 8 j-chunks); block = 256 thr = 4 waves, 16 rows/wave.
// ---------------------------------------------------------------------------
__global__ __launch_bounds__(256, 3) void k3_main(const float* __restrict__ adj,
                                                  const unsigned short* __restrict__ hT,
                                                  const float* __restrict__ As,
                                                  const float* __restrict__ Cs,
                                                  const float4* __restrict__ BD,
                                                  f16* __restrict__ Up,
                                                  float* __restrict__ Lp) {
    // +1 float4 pad every 8 so the quad-stride (32 words) lands on distinct banks
    __shared__ float4 BDl[JLEN + JLEN / 8];
    const int tid = threadIdx.x;
    const int wave = tid >> 6, lane = tid & 63;
    const int m = lane & 15, quad = lane >> 4;
    const int ibase = blockIdx.x * 64 + wave * 16;
    const int irow = ibase + m;
    const int jc = blockIdx.y;
    const int j0 = jc * JLEN;

    for (int t = tid; t < JLEN; t += 256) BDl[t + (t >> 3)] = BD[j0 + t];

    const float A0 = As[irow], C0 = Cs[irow];
    const float A1 = As[N + irow], C1 = Cs[N + irow];

    f32x4 acc[2][4];
#pragma unroll
    for (int h = 0; h < 2; ++h)
#pragma unroll
        for (int nt = 0; nt < 4; ++nt) acc[h][nt] = (f32x4){0.f, 0.f, 0.f, 0.f};
    float ls0 = 0.f, ls1 = 0.f;

    const float* adjrow = adj + (size_t)irow * N;
    __syncthreads();

    // prefetch adj for step 0
    float4 aja = *(const float4*)(adjrow + j0 + quad * 8);
    float4 ajb = *(const float4*)(adjrow + j0 + quad * 8 + 4);

#pragma unroll 1
    for (int s = 0; s < STEPS; ++s) {
        const int jq = j0 + s * 32 + quad * 8;

        // hT fragment loads for CURRENT step — issued before the P-compute
        s16x8 h0[4], h1[4];
#pragma unroll
        for (int nt = 0; nt < 4; ++nt) {
            h0[nt] = *(const s16x8*)(hT + (size_t)(nt * 16 + m) * N + jq);
            h1[nt] = *(const s16x8*)(hT + (size_t)(nt * 16 + m + 64) * N + jq);
        }

        // adj prefetch for NEXT step (wrap on last iter: valid addr, unused data)
        const int sn = (s + 1) & (STEPS - 1);
        const int jqn = j0 + sn * 32 + quad * 8;
        float4 ana = *(const float4*)(adjrow + jqn);
        float4 anb = *(const float4*)(adjrow + jqn + 4);

        // P from prefetched adj + LDS-broadcast BD
        const int bbase = s * 32 + quad * 8;
        const int bidx = bbase + (bbase >> 3);
        float ajv[8];
        *(float4*)(ajv)     = aja;
        *(float4*)(ajv + 4) = ajb;
        s16x8 p0, p1;
#pragma unroll
        for (int jj = 0; jj < 8; ++jj) {
            float4 bd = BDl[bidx + jj];
            float w0 = fmaxf(A0 * bd.x, C0 * bd.y);
            float pv0 = ajv[jj] * w0;
            ls0 += pv0;
            p0[jj] = (short)f2bf(pv0);
            float w1 = fmaxf(A1 * bd.z, C1 * bd.w);
            float pv1 = ajv[jj] * w1;
            ls1 += pv1;
            p1[jj] = (short)f2bf(pv1);
        }

#pragma unroll
        for (int nt = 0; nt < 4; ++nt) {
            acc[0][nt] = __builtin_amdgcn_mfma_f32_16x16x32_bf16(p0, h0[nt], acc[0][nt], 0, 0, 0);
            acc[1][nt] = __builtin_amdgcn_mfma_f32_16x16x32_bf16(p1, h1[nt], acc[1][nt], 0, 0, 0);
        }
        aja = ana; ajb = anb;
    }

    ls0 += __shfl_xor(ls0, 16, 64);
    ls0 += __shfl_xor(ls0, 32, 64);
    ls1 += __shfl_xor(ls1, 16, 64);
    ls1 += __shfl_xor(ls1, 32, 64);

    f16* Ub = Up + (size_t)jc * N * 128;
#pragma unroll
    for (int h = 0; h < 2; ++h)
#pragma unroll
        for (int nt = 0; nt < 4; ++nt) {
            const int c = h * 64 + nt * 16 + m;
            const int ib = ibase + quad * 4;
#pragma unroll
            for (int r = 0; r < 4; ++r)
                Ub[(size_t)(ib + r) * 128 + c] = (f16)acc[h][nt][r];
        }
    if (quad == 0) {
        Lp[((size_t)jc * 2 + 0) * N + irow] = ls0;
        Lp[((size_t)jc * 2 + 1) * N + irow] = ls1;
    }
}

// ---------------------------------------------------------------------------
// Kernel 4: sum fp16 partials over j-chunks, divide by row-sum.
// ---------------------------------------------------------------------------
__global__ __launch_bounds__(256) void k4_reduce(const f16* __restrict__ Up,
                                                 const float* __restrict__ Lp,
                                                 float* __restrict__ out) {
    const int base = (blockIdx.x * 256 + threadIdx.x) * 4;
    const int i = base >> 7, c = base & 127, h = c >> 6;
    float su0 = 0.f, su1 = 0.f, su2 = 0.f, su3 = 0.f, sl = 0.f;
#pragma unroll
    for (int jcc = 0; jcc < JC; ++jcc) {
        f16x4 u = *(const f16x4*)(Up + (size_t)jcc * N * 128 + base);
        su0 += (float)u[0]; su1 += (float)u[1];
        su2 += (float)u[2]; su3 += (float)u[3];
        sl += Lp[((size_t)jcc * 2 + h) * N + i];
    }
    float inv = 1.0f / sl;
    float4 o; o.x = su0 * inv; o.y = su1 * inv; o.z = su2 * inv; o.w = su3 * inv;
    *(float4*)(out + base) = o;
}

extern "C" void kernel_launch(void* const* d_in, const int* in_sizes, int n_in,
                              void* d_out, int out_size, void* d_ws, size_t ws_size,
                              hipStream_t stream) {
    const float* x     = (const float*)d_in[0];
    const float* adj   = (const float*)d_in[1];
    const float* W     = (const float*)d_in[2];
    const float* a_src = (const float*)d_in[3];
    const float* a_dst = (const float*)d_in[4];
    float* out = (float*)d_out;
    char* ws = (char*)d_ws;

    size_t off = 0;
    unsigned short* hT = (unsigned short*)(ws + off); off += (size_t)128 * N * 2;
    float* As = (float*)(ws + off); off += (size_t)2 * N * 4;
    float* Cs = (float*)(ws + off); off += (size_t)2 * N * 4;
    float4* BD = (float4*)(ws + off); off += (size_t)N * 16;

    f16* Up = (f16*)(ws + off);
    float* Lp = (float*)(ws + off + (size_t)JC * N * 128 * 2);

    k1_xw<<<N / 64, 256, 0, stream>>>(x, W, hT);
    k2_e<<<N / 256, 256, 0, stream>>>(hT, a_src, a_dst, As, Cs, BD);
    dim3 g3(N / 64, JC);
    k3_main<<<g3, 256, 0, stream>>>(adj, hT, As, Cs, BD, Up, Lp);
    k4_reduce<<<(N * 128) / (256 * 4), 256, 0, stream>>>(Up, Lp, out);
}

// Round 4
// 455.787 us; speedup vs baseline: 1.2270x; 1.1824x over previous
//
#include <hip/hip_runtime.h>
#include <hip/hip_bf16.h>

#define N 8192
#define IND 128
#define OUTD 128
#define JC 8
#define JLEN 1024   /* N/JC */
#define STEPS 32    /* JLEN/32, BK=32 */

typedef float f32x4 __attribute__((ext_vector_type(4)));
typedef short s16x8 __attribute__((ext_vector_type(8)));
typedef _Float16 f16;
typedef _Float16 f16x4 __attribute__((ext_vector_type(4)));

static __device__ inline unsigned short f2bf(float f) {
    union { float f; unsigned u; } v; v.f = f;
    unsigned u = v.u + 0x7fffu + ((v.u >> 16) & 1u);
    return (unsigned short)(u >> 16);
}
static __device__ inline float bf2f(unsigned short b) {
    union { unsigned u; float f; } v; v.u = ((unsigned)b) << 16;
    return v.f;
}

// async 16B/lane global->LDS: lds dest = uniform base + lane*16
static __device__ __forceinline__ void async16(const void* g, void* l) {
    __builtin_amdgcn_global_load_lds(
        (const __attribute__((address_space(1))) unsigned int*)g,
        (__attribute__((address_space(3))) unsigned int*)l, 16, 0, 0);
}

// ---------------------------------------------------------------------------
// Kernel 1: h = x @ W  (bf16 MFMA), store transposed bf16 hT[c][i] (128 x N).
// ---------------------------------------------------------------------------
__global__ __launch_bounds__(256) void k1_xw(const float* __restrict__ x,
                                             const float* __restrict__ W,
                                             unsigned short* __restrict__ hT) {
    __shared__ unsigned short Wl[128 * 130];
    const int tid = threadIdx.x;
    {
        int k = tid >> 1, n0 = (tid & 1) * 64;
        const float4* src = (const float4*)(W + k * 128 + n0);
#pragma unroll
        for (int v = 0; v < 16; ++v) {
            float4 f = src[v];
            int base = k * 130 + n0 + v * 4;
            Wl[base + 0] = f2bf(f.x);
            Wl[base + 1] = f2bf(f.y);
            Wl[base + 2] = f2bf(f.z);
            Wl[base + 3] = f2bf(f.w);
        }
    }
    __syncthreads();
    const int wave = tid >> 6, lane = tid & 63;
    const int m = lane & 15, quad = lane >> 4;
    const int ibase = blockIdx.x * 64 + wave * 16;
    const int irow = ibase + m;

    f32x4 acc[8];
#pragma unroll
    for (int t = 0; t < 8; ++t) acc[t] = (f32x4){0.f, 0.f, 0.f, 0.f};

#pragma unroll
    for (int ks = 0; ks < 4; ++ks) {
        const int k0 = ks * 32 + quad * 8;
        const float4* xp = (const float4*)(x + (size_t)irow * 128 + k0);
        float4 xa = xp[0], xb = xp[1];
        s16x8 afrag;
        afrag[0] = (short)f2bf(xa.x); afrag[1] = (short)f2bf(xa.y);
        afrag[2] = (short)f2bf(xa.z); afrag[3] = (short)f2bf(xa.w);
        afrag[4] = (short)f2bf(xb.x); afrag[5] = (short)f2bf(xb.y);
        afrag[6] = (short)f2bf(xb.z); afrag[7] = (short)f2bf(xb.w);
#pragma unroll
        for (int nt = 0; nt < 8; ++nt) {
            const int n = nt * 16 + m;
            s16x8 bfrag;
#pragma unroll
            for (int j = 0; j < 8; ++j)
                bfrag[j] = (short)Wl[(k0 + j) * 130 + n];
            acc[nt] = __builtin_amdgcn_mfma_f32_16x16x32_bf16(afrag, bfrag, acc[nt], 0, 0, 0);
        }
    }
#pragma unroll
    for (int nt = 0; nt < 8; ++nt) {
        const int c = nt * 16 + m;
        const int i0 = ibase + quad * 4;
        ushort4 pk;
        pk.x = f2bf(acc[nt][0]); pk.y = f2bf(acc[nt][1]);
        pk.z = f2bf(acc[nt][2]); pk.w = f2bf(acc[nt][3]);
        *(ushort4*)(hT + (size_t)c * N + i0) = pk;
    }
}

// ---------------------------------------------------------------------------
// Kernel 2: per-node separable arrays.
// w_ij = exp(leaky(es_i + ed_j)) = max(A_i*B_j, C_i*D_j);  BD[j]={B0,D0,B1,D1}
// ---------------------------------------------------------------------------
__global__ __launch_bounds__(256) void k2_e(const unsigned short* __restrict__ hT,
                                            const float* __restrict__ a_src,
                                            const float* __restrict__ a_dst,
                                            float* __restrict__ As, float* __restrict__ Cs,
                                            float4* __restrict__ BD) {
    const int i = blockIdx.x * 256 + threadIdx.x;
    float es0 = 0.f, ed0 = 0.f, es1 = 0.f, ed1 = 0.f;
#pragma unroll 8
    for (int c = 0; c < 128; ++c) {
        float v = bf2f(hT[(size_t)c * N + i]);
        float as = a_src[c], ad = a_dst[c];
        if (c < 64) { es0 += v * as; ed0 += v * ad; }
        else        { es1 += v * as; ed1 += v * ad; }
    }
    As[i]     = __expf(es0);
    As[N + i] = __expf(es1);
    Cs[i]     = __expf(0.2f * es0);
    Cs[N + i] = __expf(0.2f * es1);
    float4 bd;
    bd.x = __expf(ed0); bd.y = __expf(0.2f * ed0);
    bd.z = __expf(ed1); bd.w = __expf(0.2f * ed1);
    BD[i] = bd;
}

// ---------------------------------------------------------------------------
// Kernel 3 (main): m97-style global_load_lds double-buffered K-loop.
//  - adj: per-lane-private slots (lane reads back what it staged) -> 0 conflicts
//  - hT : slot-rotated chunks, rotation (q + (m>>1))&3 -> <=2-way (free)
//  - BD : staged once, broadcast reads (free)
// grid = (128 i-tiles, 8 j-chunks); block = 256 thr = 4 waves, 16 rows/wave.
// ---------------------------------------------------------------------------
__global__ __launch_bounds__(256, 3) void k3_main(const float* __restrict__ adj,
                                                  const unsigned short* __restrict__ hT,
                                                  const float* __restrict__ As,
                                                  const float* __restrict__ Cs,
                                                  const float4* __restrict__ BD,
                                                  f16* __restrict__ Up,
                                                  float* __restrict__ Lp) {
    __shared__ float4 BDl[JLEN];              // 16 KB
    __shared__ float4 adjbuf[2][4][2][64];    // 16 KB [buf][wave][half][slot]
    __shared__ float4 hbuf[2][8][64];         // 16 KB [buf][chunk][slot]

    const int tid = threadIdx.x;
    const int wave = tid >> 6, lane = tid & 63;
    const int m = lane & 15, quad = lane >> 4;
    const int ibase = blockIdx.x * 64 + wave * 16;
    const int irow = ibase + m;
    const int jc = blockIdx.y;
    const int j0 = jc * JLEN;

    const float A0 = As[irow], C0 = Cs[irow];
    const float A1 = As[N + irow], C1 = Cs[N + irow];

    f32x4 acc[2][4];
#pragma unroll
    for (int h = 0; h < 2; ++h)
#pragma unroll
        for (int nt = 0; nt < 4; ++nt) acc[h][nt] = (f32x4){0.f, 0.f, 0.f, 0.f};
    float ls0 = 0.f, ls1 = 0.f;

    const float* adjrow = adj + (size_t)irow * N;     // reader row (slot==lane)
    const size_t adjsrow = (size_t)(ibase + (lane & 15)) * N;  // stager row

    // stage rotation params (stager view)
    const int hr = lane >> 2;                  // row within hT chunk (0..15)
    const int hcs = ((lane & 3) - ((hr >> 1) & 3)) & 3;  // rotated col slot

    // ---- prologue: BD (whole chunk) + buffer 0 for step 0 ----
#pragma unroll
    for (int c = 0; c < 4; ++c)
        async16(BD + j0 + (wave * 4 + c) * 64 + lane, &BDl[(wave * 4 + c) * 64]);
    {
        const int jb = j0;
        async16(adj + adjsrow + jb + (lane >> 4) * 8,     &adjbuf[0][wave][0][0]);
        async16(adj + adjsrow + jb + (lane >> 4) * 8 + 4, &adjbuf[0][wave][1][0]);
#pragma unroll
        for (int cc = 0; cc < 2; ++cc) {
            const int g = wave * 2 + cc;
            async16(hT + (size_t)(g * 16 + hr) * N + jb + hcs * 8, &hbuf[0][g][0]);
        }
    }
    __syncthreads();

    const int slotp = (quad + ((m >> 1) & 3)) & 3;   // reader's rotated hT slot

#pragma unroll 1
    for (int s = 0; s < STEPS; ++s) {
        const int p = s & 1;
        // stage next step into the other buffer (nobody reads it this step)
        if (s + 1 < STEPS) {
            const int pb = p ^ 1;
            const int jb = j0 + (s + 1) * 32;
            async16(adj + adjsrow + jb + (lane >> 4) * 8,     &adjbuf[pb][wave][0][0]);
            async16(adj + adjsrow + jb + (lane >> 4) * 8 + 4, &adjbuf[pb][wave][1][0]);
#pragma unroll
            for (int cc = 0; cc < 2; ++cc) {
                const int g = wave * 2 + cc;
                async16(hT + (size_t)(g * 16 + hr) * N + jb + hcs * 8, &hbuf[pb][g][0]);
            }
        }

        // ---- compute from buffer p ----
        float4 aja = adjbuf[p][wave][0][lane];   // own slot: conflict-free
        float4 ajb = adjbuf[p][wave][1][lane];
        float ajv[8];
        *(float4*)(ajv)     = aja;
        *(float4*)(ajv + 4) = ajb;

        s16x8 h0[4], h1[4];
#pragma unroll
        for (int nt = 0; nt < 4; ++nt) {
            h0[nt] = *(const s16x8*)&hbuf[p][nt][m * 4 + slotp];
            h1[nt] = *(const s16x8*)&hbuf[p][4 + nt][m * 4 + slotp];
        }

        s16x8 p0, p1;
        const int bb = s * 32 + quad * 8;
#pragma unroll
        for (int jj = 0; jj < 8; ++jj) {
            float4 bd = BDl[bb + jj];            // broadcast: conflict-free
            float w0 = fmaxf(A0 * bd.x, C0 * bd.y);
            float pv0 = ajv[jj] * w0;
            ls0 += pv0;
            p0[jj] = (short)f2bf(pv0);
            float w1 = fmaxf(A1 * bd.z, C1 * bd.w);
            float pv1 = ajv[jj] * w1;
            ls1 += pv1;
            p1[jj] = (short)f2bf(pv1);
        }

#pragma unroll
        for (int nt = 0; nt < 4; ++nt) {
            acc[0][nt] = __builtin_amdgcn_mfma_f32_16x16x32_bf16(p0, h0[nt], acc[0][nt], 0, 0, 0);
            acc[1][nt] = __builtin_amdgcn_mfma_f32_16x16x32_bf16(p1, h1[nt], acc[1][nt], 0, 0, 0);
        }

        __syncthreads();   // drains staging vmcnt; gates reuse of buffer p
    }

    ls0 += __shfl_xor(ls0, 16, 64);
    ls0 += __shfl_xor(ls0, 32, 64);
    ls1 += __shfl_xor(ls1, 16, 64);
    ls1 += __shfl_xor(ls1, 32, 64);

    f16* Ub = Up + (size_t)jc * N * 128;
#pragma unroll
    for (int h = 0; h < 2; ++h)
#pragma unroll
        for (int nt = 0; nt < 4; ++nt) {
            const int c = h * 64 + nt * 16 + m;
            const int ib = ibase + quad * 4;
#pragma unroll
            for (int r = 0; r < 4; ++r)
                Ub[(size_t)(ib + r) * 128 + c] = (f16)acc[h][nt][r];
        }
    if (quad == 0) {
        Lp[((size_t)jc * 2 + 0) * N + irow] = ls0;
        Lp[((size_t)jc * 2 + 1) * N + irow] = ls1;
    }
    (void)adjrow;
}

// ---------------------------------------------------------------------------
// Kernel 4: sum fp16 partials over j-chunks, divide by row-sum.
// ---------------------------------------------------------------------------
__global__ __launch_bounds__(256) void k4_reduce(const f16* __restrict__ Up,
                                                 const float* __restrict__ Lp,
                                                 float* __restrict__ out) {
    const int base = (blockIdx.x * 256 + threadIdx.x) * 4;
    const int i = base >> 7, c = base & 127, h = c >> 6;
    float su0 = 0.f, su1 = 0.f, su2 = 0.f, su3 = 0.f, sl = 0.f;
#pragma unroll
    for (int jcc = 0; jcc < JC; ++jcc) {
        f16x4 u = *(const f16x4*)(Up + (size_t)jcc * N * 128 + base);
        su0 += (float)u[0]; su1 += (float)u[1];
        su2 += (float)u[2]; su3 += (float)u[3];
        sl += Lp[((size_t)jcc * 2 + h) * N + i];
    }
    float inv = 1.0f / sl;
    float4 o; o.x = su0 * inv; o.y = su1 * inv; o.z = su2 * inv; o.w = su3 * inv;
    *(float4*)(out + base) = o;
}

extern "C" void kernel_launch(void* const* d_in, const int* in_sizes, int n_in,
                              void* d_out, int out_size, void* d_ws, size_t ws_size,
                              hipStream_t stream) {
    const float* x     = (const float*)d_in[0];
    const float* adj   = (const float*)d_in[1];
    const float* W     = (const float*)d_in[2];
    const float* a_src = (const float*)d_in[3];
    const float* a_dst = (const float*)d_in[4];
    float* out = (float*)d_out;
    char* ws = (char*)d_ws;

    size_t off = 0;
    unsigned short* hT = (unsigned short*)(ws + off); off += (size_t)128 * N * 2;
    float* As = (float*)(ws + off); off += (size_t)2 * N * 4;
    float* Cs = (float*)(ws + off); off += (size_t)2 * N * 4;
    float4* BD = (float4*)(ws + off); off += (size_t)N * 16;

    f16* Up = (f16*)(ws + off);
    float* Lp = (float*)(ws + off + (size_t)JC * N * 128 * 2);

    k1_xw<<<N / 64, 256, 0, stream>>>(x, W, hT);
    k2_e<<<N / 256, 256, 0, stream>>>(hT, a_src, a_dst, As, Cs, BD);
    dim3 g3(N / 64, JC);
    k3_main<<<g3, 256, 0, stream>>>(adj, hT, As, Cs, BD, Up, Lp);
    k4_reduce<<<(N * 128) / (256 * 4), 256, 0, stream>>>(Up, Lp, out);
}